// Round 1
// baseline (1430.491 us; speedup 1.0000x reference)
//
#include <hip/hip_runtime.h>

#define DIM 128
#define NLAYERS 3
#define NGRAPHS 128
#define BN_EPS 1e-5f

// ---------------- CSR build ----------------

__global__ __launch_bounds__(256) void hist_kernel(const int* __restrict__ dst,
                                                   int* __restrict__ deg, int E) {
  int e = blockIdx.x * 256 + threadIdx.x;
  if (e < E) atomicAdd(&deg[dst[e]], 1);
}

__global__ __launch_bounds__(1024) void scan_kernel(const int* __restrict__ deg,
                                                    int* __restrict__ offsets,
                                                    int* __restrict__ cursor, int n) {
  __shared__ int part[1024];
  int t = threadIdx.x;
  int chunk = (n + 1023) >> 10;
  int lo = t * chunk, hi = min(lo + chunk, n);
  int s = 0;
  for (int j = lo; j < hi; ++j) s += deg[j];
  part[t] = s;
  __syncthreads();
  for (int off = 1; off < 1024; off <<= 1) {
    int v = (t >= off) ? part[t - off] : 0;
    __syncthreads();
    part[t] += v;
    __syncthreads();
  }
  int run = (t == 0) ? 0 : part[t - 1];
  for (int j = lo; j < hi; ++j) {
    offsets[j] = run;
    cursor[j] = run;
    run += deg[j];
  }
  if (t == 1023) offsets[n] = part[1023];
}

__global__ __launch_bounds__(256) void scatter_kernel(const int* __restrict__ src,
                                                      const int* __restrict__ dst,
                                                      int* __restrict__ cursor,
                                                      int* __restrict__ eidx, int E) {
  int e = blockIdx.x * 256 + threadIdx.x;
  if (e < E) {
    int p = atomicAdd(&cursor[dst[e]], 1);
    eidx[p] = src[e];
  }
}

// ---------------- aggregation: z = h + sum_{j->i} h[j] ----------------
// one wave per node, lane owns dims {2l, 2l+1}

__global__ __launch_bounds__(256) void agg_kernel(const float* __restrict__ hin,
                                                  const int* __restrict__ offsets,
                                                  const int* __restrict__ eidx,
                                                  float* __restrict__ zout,
                                                  float* __restrict__ gstats, int N) {
  if (blockIdx.x == 0) gstats[threadIdx.x] = 0.f;  // zero sum[128]+sumsq[128] for this layer
  int wid = (blockIdx.x * 256 + threadIdx.x) >> 6;
  int lane = threadIdx.x & 63;
  if (wid >= N) return;
  const float2* h2 = (const float2*)hin;
  float2 acc = h2[(size_t)wid * 64 + lane];
  int beg = offsets[wid], end = offsets[wid + 1];
  int e = beg;
  for (; e + 1 < end; e += 2) {
    int s0 = eidx[e], s1 = eidx[e + 1];
    float2 v0 = h2[(size_t)s0 * 64 + lane];
    float2 v1 = h2[(size_t)s1 * 64 + lane];
    acc.x += v0.x; acc.y += v0.y;
    acc.x += v1.x; acc.y += v1.y;
  }
  if (e < end) {
    int s0 = eidx[e];
    float2 v0 = h2[(size_t)s0 * 64 + lane];
    acc.x += v0.x; acc.y += v0.y;
  }
  ((float2*)zout)[(size_t)wid * 64 + lane] = acc;
}

// ---------------- fused MLP: u = relu(relu(z@W1+b1)@W2+b2), in-place, + BN stats ----------------
// block 256, 64-node tile; thread = 4 nodes x 8 dims micro-tile

__global__ __launch_bounds__(256) void mlp_kernel(float* __restrict__ zio,
                                                  const float* __restrict__ W1,
                                                  const float* __restrict__ b1,
                                                  const float* __restrict__ W2,
                                                  const float* __restrict__ b2,
                                                  float* __restrict__ gstats, int N) {
  __shared__ float zt[64 * 132];   // pad 132 to reduce bank conflicts
  __shared__ float sstat[256];
  int tid = threadIdx.x;
  int nbase = blockIdx.x * 64;
  sstat[tid] = 0.f;

  // stage z tile
  for (int idx = tid; idx < 64 * 32; idx += 256) {
    int r = idx >> 5, c4 = (idx & 31) << 2;
    int n = nbase + r;
    float4 v = make_float4(0.f, 0.f, 0.f, 0.f);
    if (n < N) v = *(const float4*)&zio[(size_t)n * 128 + c4];
    *(float4*)&zt[r * 132 + c4] = v;
  }
  __syncthreads();

  int dg = tid & 15, ng = tid >> 4;
  int d0 = dg << 3;
  int r0 = ng << 2;
  int lane = tid & 63;
  float acc[4][8];

  // ---- GEMM1: t = relu(z @ W1 + b1) ----
#pragma unroll
  for (int j = 0; j < 8; ++j) {
    float bv = b1[d0 + j];
    acc[0][j] = bv; acc[1][j] = bv; acc[2][j] = bv; acc[3][j] = bv;
  }
  for (int k = 0; k < 128; k += 2) {
    float2 z0 = *(const float2*)&zt[(r0 + 0) * 132 + k];
    float2 z1 = *(const float2*)&zt[(r0 + 1) * 132 + k];
    float2 z2 = *(const float2*)&zt[(r0 + 2) * 132 + k];
    float2 z3 = *(const float2*)&zt[(r0 + 3) * 132 + k];
    float4 a0 = *(const float4*)&W1[k * 128 + d0];
    float4 a1 = *(const float4*)&W1[k * 128 + d0 + 4];
    float4 c0 = *(const float4*)&W1[(k + 1) * 128 + d0];
    float4 c1 = *(const float4*)&W1[(k + 1) * 128 + d0 + 4];
    float wk0[8] = {a0.x, a0.y, a0.z, a0.w, a1.x, a1.y, a1.z, a1.w};
    float wk1[8] = {c0.x, c0.y, c0.z, c0.w, c1.x, c1.y, c1.z, c1.w};
    float zx[4] = {z0.x, z1.x, z2.x, z3.x};
    float zy[4] = {z0.y, z1.y, z2.y, z3.y};
#pragma unroll
    for (int i = 0; i < 4; ++i)
#pragma unroll
      for (int j = 0; j < 8; ++j)
        acc[i][j] += zx[i] * wk0[j] + zy[i] * wk1[j];
  }
  __syncthreads();
  // stage t (relu) into LDS
#pragma unroll
  for (int i = 0; i < 4; ++i) {
    float4 t0 = make_float4(fmaxf(acc[i][0], 0.f), fmaxf(acc[i][1], 0.f),
                            fmaxf(acc[i][2], 0.f), fmaxf(acc[i][3], 0.f));
    float4 t1 = make_float4(fmaxf(acc[i][4], 0.f), fmaxf(acc[i][5], 0.f),
                            fmaxf(acc[i][6], 0.f), fmaxf(acc[i][7], 0.f));
    *(float4*)&zt[(r0 + i) * 132 + d0] = t0;
    *(float4*)&zt[(r0 + i) * 132 + d0 + 4] = t1;
  }
  __syncthreads();

  // ---- GEMM2: u = relu(t @ W2 + b2) ----
#pragma unroll
  for (int j = 0; j < 8; ++j) {
    float bv = b2[d0 + j];
    acc[0][j] = bv; acc[1][j] = bv; acc[2][j] = bv; acc[3][j] = bv;
  }
  for (int k = 0; k < 128; k += 2) {
    float2 z0 = *(const float2*)&zt[(r0 + 0) * 132 + k];
    float2 z1 = *(const float2*)&zt[(r0 + 1) * 132 + k];
    float2 z2 = *(const float2*)&zt[(r0 + 2) * 132 + k];
    float2 z3 = *(const float2*)&zt[(r0 + 3) * 132 + k];
    float4 a0 = *(const float4*)&W2[k * 128 + d0];
    float4 a1 = *(const float4*)&W2[k * 128 + d0 + 4];
    float4 c0 = *(const float4*)&W2[(k + 1) * 128 + d0];
    float4 c1 = *(const float4*)&W2[(k + 1) * 128 + d0 + 4];
    float wk0[8] = {a0.x, a0.y, a0.z, a0.w, a1.x, a1.y, a1.z, a1.w};
    float wk1[8] = {c0.x, c0.y, c0.z, c0.w, c1.x, c1.y, c1.z, c1.w};
    float zx[4] = {z0.x, z1.x, z2.x, z3.x};
    float zy[4] = {z0.y, z1.y, z2.y, z3.y};
#pragma unroll
    for (int i = 0; i < 4; ++i)
#pragma unroll
      for (int j = 0; j < 8; ++j)
        acc[i][j] += zx[i] * wk0[j] + zy[i] * wk1[j];
  }

  // relu, zero invalid rows, store u in place, accumulate stats
#pragma unroll
  for (int i = 0; i < 4; ++i) {
    int n = nbase + r0 + i;
    bool valid = n < N;
#pragma unroll
    for (int j = 0; j < 8; ++j) {
      float u = fmaxf(acc[i][j], 0.f);
      acc[i][j] = valid ? u : 0.f;
    }
    if (valid) {
      float4 u0 = make_float4(acc[i][0], acc[i][1], acc[i][2], acc[i][3]);
      float4 u1 = make_float4(acc[i][4], acc[i][5], acc[i][6], acc[i][7]);
      *(float4*)&zio[(size_t)n * 128 + d0] = u0;
      *(float4*)&zio[(size_t)n * 128 + d0 + 4] = u1;
    }
  }
#pragma unroll
  for (int j = 0; j < 8; ++j) {
    float s = acc[0][j] + acc[1][j] + acc[2][j] + acc[3][j];
    float q = acc[0][j] * acc[0][j] + acc[1][j] * acc[1][j] +
              acc[2][j] * acc[2][j] + acc[3][j] * acc[3][j];
    s += __shfl_xor(s, 16); s += __shfl_xor(s, 32);
    q += __shfl_xor(q, 16); q += __shfl_xor(q, 32);
    if (lane < 16) {
      atomicAdd(&sstat[lane * 8 + j], s);
      atomicAdd(&sstat[128 + lane * 8 + j], q);
    }
  }
  __syncthreads();
  atomicAdd(&gstats[tid], sstat[tid]);
}

// ---------------- BN finalize: fold stats into scale/shift ----------------

__global__ __launch_bounds__(128) void bn_finalize_kernel(float* __restrict__ gstats,
                                                          const float* __restrict__ gamma,
                                                          const float* __restrict__ beta,
                                                          float invN) {
  int d = threadIdx.x;
  float mu = gstats[d] * invN;
  float var = gstats[128 + d] * invN - mu * mu;
  float sc = gamma[d] * rsqrtf(var + BN_EPS);
  gstats[256 + d] = sc;
  gstats[384 + d] = beta[d] - mu * sc;
}

// ---------------- BN apply + segment pool (batch is sorted) ----------------

__global__ __launch_bounds__(256) void bn_pool_kernel(const float* __restrict__ u,
                                                      const float* __restrict__ gstats,
                                                      const int* __restrict__ batch,
                                                      float* __restrict__ hout,
                                                      float* __restrict__ pool,
                                                      int poolcol, int N) {
  int d = threadIdx.x & 127;
  int half = threadIdx.x >> 7;
  int base = blockIdx.x * 256;
  float sc = gstats[256 + d], sh = gstats[384 + d];
  int curg = -1;
  float accp = 0.f;
  for (int r = half; r < 256; r += 2) {
    int n = base + r;
    if (n >= N) break;
    float h = u[(size_t)n * 128 + d] * sc + sh;
    hout[(size_t)n * 128 + d] = h;
    int g = batch[n];
    if (g != curg) {
      if (curg >= 0) atomicAdd(&pool[(size_t)curg * (NLAYERS * DIM) + poolcol + d], accp);
      curg = g;
      accp = 0.f;
    }
    accp += h;
  }
  if (curg >= 0) atomicAdd(&pool[(size_t)curg * (NLAYERS * DIM) + poolcol + d], accp);
}

// ---------------- launch ----------------

extern "C" void kernel_launch(void* const* d_in, const int* in_sizes, int n_in,
                              void* d_out, int out_size, void* d_ws, size_t ws_size,
                              hipStream_t stream) {
  const float* x = (const float*)d_in[0];
  const int* edge = (const int*)d_in[1];
  const int* batch = (const int*)d_in[2];
  const float* W1 = (const float*)d_in[3];
  const float* b1 = (const float*)d_in[4];
  const float* W2 = (const float*)d_in[5];
  const float* b2 = (const float*)d_in[6];
  const float* gamma = (const float*)d_in[7];
  const float* beta = (const float*)d_in[8];

  int N = in_sizes[0] / DIM;
  int E = in_sizes[1] / 2;
  const int* src = edge;
  const int* dst = edge + E;

  int* deg = (int*)d_ws;
  int* offsets = deg + N;
  int* cursor = offsets + N + 1;
  int* eidx = cursor + N;
  float* gstats = (float*)(eidx + E);
  uintptr_t zp = (uintptr_t)(gstats + 512);
  zp = (zp + 255) & ~(uintptr_t)255;
  float* zbuf = (float*)zp;

  float* pool = (float*)d_out;
  float* hbuf = (float*)d_out + (size_t)NGRAPHS * NLAYERS * DIM;

  hipMemsetAsync(deg, 0, (size_t)N * 4, stream);
  hipMemsetAsync(pool, 0, (size_t)NGRAPHS * NLAYERS * DIM * 4, stream);

  int eb = (E + 255) / 256;
  hist_kernel<<<eb, 256, 0, stream>>>(dst, deg, E);
  scan_kernel<<<1, 1024, 0, stream>>>(deg, offsets, cursor, N);
  scatter_kernel<<<eb, 256, 0, stream>>>(src, dst, cursor, eidx, E);

  const float* hin = x;
  for (int L = 0; L < NLAYERS; ++L) {
    agg_kernel<<<(N + 3) / 4, 256, 0, stream>>>(hin, offsets, eidx, zbuf, gstats, N);
    mlp_kernel<<<(N + 63) / 64, 256, 0, stream>>>(zbuf, W1 + (size_t)L * DIM * DIM,
                                                  b1 + L * DIM, W2 + (size_t)L * DIM * DIM,
                                                  b2 + L * DIM, gstats, N);
    bn_finalize_kernel<<<1, 128, 0, stream>>>(gstats, gamma + L * DIM, beta + L * DIM,
                                              1.0f / (float)N);
    bn_pool_kernel<<<(N + 255) / 256, 256, 0, stream>>>(zbuf, gstats, batch, hbuf, pool,
                                                        L * DIM, N);
    hin = hbuf;
  }
}

// Round 2
// 832.635 us; speedup vs baseline: 1.7180x; 1.7180x over previous
//
#include <hip/hip_runtime.h>

#define DIM 128
#define NLAYERS 3
#define NGRAPHS 128
#define BN_EPS 1e-5f

typedef __attribute__((ext_vector_type(8))) short short8v;
typedef __attribute__((ext_vector_type(8))) unsigned short ushort8v;
typedef __attribute__((ext_vector_type(4))) float f32x4;

__device__ __forceinline__ unsigned short f2bf(float f) {
  unsigned int x = __float_as_uint(f);
  unsigned int r = (x + 0x7fffu + ((x >> 16) & 1u)) >> 16;  // RTNE
  return (unsigned short)r;
}
__device__ __forceinline__ float bflo(unsigned int u) { return __uint_as_float(u << 16); }
__device__ __forceinline__ float bfhi(unsigned int u) { return __uint_as_float(u & 0xffff0000u); }

// ---------------- CSR build ----------------

__global__ __launch_bounds__(256) void hist_kernel(const int* __restrict__ dst,
                                                   int* __restrict__ deg, int E) {
  int e = blockIdx.x * 256 + threadIdx.x;
  if (e < E) atomicAdd(&deg[dst[e]], 1);
}

// parallel scan: per-1024-chunk reduce -> scan partials -> per-chunk scan+apply
__global__ __launch_bounds__(256) void red_kernel(const int* __restrict__ deg,
                                                  int* __restrict__ part, int N) {
  int base = blockIdx.x * 1024;
  int s = 0;
  for (int j = threadIdx.x; j < 1024; j += 256) {
    int i = base + j;
    if (i < N) s += deg[i];
  }
  for (int off = 1; off < 64; off <<= 1) s += __shfl_xor(s, off);
  __shared__ int wsum[4];
  if ((threadIdx.x & 63) == 0) wsum[threadIdx.x >> 6] = s;
  __syncthreads();
  if (threadIdx.x == 0) part[blockIdx.x] = wsum[0] + wsum[1] + wsum[2] + wsum[3];
}

__global__ __launch_bounds__(128) void scanpart_kernel(int* __restrict__ part, int B) {
  __shared__ int p[128];
  int t = threadIdx.x;
  p[t] = (t < B) ? part[t] : 0;
  __syncthreads();
  for (int off = 1; off < 128; off <<= 1) {
    int v = (t >= off) ? p[t - off] : 0;
    __syncthreads();
    p[t] += v;
    __syncthreads();
  }
  if (t < B) part[t] = (t == 0) ? 0 : p[t - 1];
}

__global__ __launch_bounds__(256) void bscan_kernel(const int* __restrict__ deg,
                                                    const int* __restrict__ part,
                                                    int* __restrict__ offsets,
                                                    int* __restrict__ cursor, int N) {
  int base = blockIdx.x * 1024 + threadIdx.x * 4;
  int v0 = 0, v1 = 0, v2 = 0, v3 = 0;
  if (base + 3 < N) {
    int4 q = *(const int4*)&deg[base];
    v0 = q.x; v1 = q.y; v2 = q.z; v3 = q.w;
  } else {
    if (base < N) v0 = deg[base];
    if (base + 1 < N) v1 = deg[base + 1];
    if (base + 2 < N) v2 = deg[base + 2];
    if (base + 3 < N) v3 = deg[base + 3];
  }
  int T = v0 + v1 + v2 + v3;
  int inc = T;
  int lane = threadIdx.x & 63;
  for (int off = 1; off < 64; off <<= 1) {
    int u = __shfl_up(inc, off);
    if (lane >= off) inc += u;
  }
  __shared__ int wt[4];
  if (lane == 63) wt[threadIdx.x >> 6] = inc;
  __syncthreads();
  int wid = threadIdx.x >> 6;
  int wbase = 0;
  for (int i = 0; i < 4; ++i)
    if (i < wid) wbase += wt[i];
  int tbase = part[blockIdx.x] + wbase + (inc - T);
  int o0 = tbase, o1 = o0 + v0, o2 = o1 + v1, o3 = o2 + v2;
  if (base < N) { offsets[base] = o0; cursor[base] = o0; }
  if (base + 1 < N) { offsets[base + 1] = o1; cursor[base + 1] = o1; }
  if (base + 2 < N) { offsets[base + 2] = o2; cursor[base + 2] = o2; }
  if (base + 3 < N) { offsets[base + 3] = o3; cursor[base + 3] = o3; }
  int j = N - 1 - base;
  if (j == 0) offsets[N] = o0 + v0;
  else if (j == 1) offsets[N] = o1 + v1;
  else if (j == 2) offsets[N] = o2 + v2;
  else if (j == 3) offsets[N] = o3 + v3;
}

__global__ __launch_bounds__(256) void scatter_kernel(const int* __restrict__ src,
                                                      const int* __restrict__ dst,
                                                      int* __restrict__ cursor,
                                                      int* __restrict__ eidx, int E) {
  int e = blockIdx.x * 256 + threadIdx.x;
  if (e < E) {
    int p = atomicAdd(&cursor[dst[e]], 1);
    eidx[p] = src[e];
  }
}

// ---------------- conversions ----------------

__global__ __launch_bounds__(256) void convx_kernel(const float* __restrict__ x,
                                                    unsigned short* __restrict__ out,
                                                    int nquads) {
  int i = blockIdx.x * 256 + threadIdx.x;
  if (i < nquads) {
    float4 v = ((const float4*)x)[i];
    ushort4 o;
    o.x = f2bf(v.x); o.y = f2bf(v.y); o.z = f2bf(v.z); o.w = f2bf(v.w);
    ((ushort4*)out)[i] = o;
  }
}

// transpose+convert 6 weight matrices [128][128]: Wt[m][n][k] = W[k][n]
__global__ __launch_bounds__(256) void convw_kernel(const float* __restrict__ W1,
                                                    const float* __restrict__ W2,
                                                    unsigned short* __restrict__ Wt) {
  int m = blockIdx.x;
  const float* W = (m < 3) ? (W1 + (size_t)m * 16384) : (W2 + (size_t)(m - 3) * 16384);
  unsigned short* out = Wt + (size_t)m * 16384;
  __shared__ unsigned short t[128 * 130];
  for (int i = threadIdx.x; i < 16384; i += 256) {
    int k = i >> 7, n = i & 127;
    t[n * 130 + k] = f2bf(W[i]);
  }
  __syncthreads();
  for (int i = threadIdx.x; i < 16384; i += 256) {
    int n = i >> 7, k = i & 127;
    out[i] = t[n * 130 + k];
  }
}

// ---------------- aggregation: z = h + sum_{j->i} h[j] (bf16 in/out, f32 accum) ----------------

__global__ __launch_bounds__(256) void agg_kernel(const unsigned short* __restrict__ hin,
                                                  const int* __restrict__ offsets,
                                                  const int* __restrict__ eidx,
                                                  unsigned short* __restrict__ zout,
                                                  float* __restrict__ gstats, int N) {
  if (blockIdx.x == 0) gstats[threadIdx.x] = 0.f;  // zero sum[128]+sumsq[128]
  int wid = (blockIdx.x * 256 + threadIdx.x) >> 6;
  int lane = threadIdx.x & 63;
  if (wid >= N) return;
  const unsigned int* h32 = (const unsigned int*)hin;
  unsigned int own = h32[(size_t)wid * 64 + lane];
  float ax = bflo(own), ay = bfhi(own);
  int beg = offsets[wid], end = offsets[wid + 1];
  int e = beg;
  for (; e + 3 < end; e += 4) {
    int s0 = eidx[e], s1 = eidx[e + 1], s2 = eidx[e + 2], s3 = eidx[e + 3];
    unsigned int u0 = h32[(size_t)s0 * 64 + lane];
    unsigned int u1 = h32[(size_t)s1 * 64 + lane];
    unsigned int u2 = h32[(size_t)s2 * 64 + lane];
    unsigned int u3 = h32[(size_t)s3 * 64 + lane];
    ax += bflo(u0) + bflo(u1) + bflo(u2) + bflo(u3);
    ay += bfhi(u0) + bfhi(u1) + bfhi(u2) + bfhi(u3);
  }
  for (; e < end; ++e) {
    unsigned int u0 = h32[(size_t)eidx[e] * 64 + lane];
    ax += bflo(u0);
    ay += bfhi(u0);
  }
  unsigned int packed = (unsigned int)f2bf(ax) | ((unsigned int)f2bf(ay) << 16);
  ((unsigned int*)zout)[(size_t)wid * 64 + lane] = packed;
}

// ---------------- fused MLP via MFMA: u = relu(relu(z@W1+b1)@W2+b2) ----------------
// block 256 = 4 waves; tile 128 nodes x 128 dims; wave w owns rows [w*32, w*32+32)
// A-frag: row=lane&15, k=(lane>>4)*8+j ; B-frag (from W^T): col=lane&15, k contig
// D-frag: row=(lane>>4)*4+q, col=lane&15

__global__ __launch_bounds__(256) void mlp_kernel(unsigned short* __restrict__ zio,
                                                  const unsigned short* __restrict__ WtA,
                                                  const float* __restrict__ b1,
                                                  const unsigned short* __restrict__ WtB,
                                                  const float* __restrict__ b2,
                                                  float* __restrict__ gstats, int N) {
  __shared__ unsigned short zt[128 * 136];
  __shared__ unsigned short tt[128 * 136];
  __shared__ float sstat[256];
  int tid = threadIdx.x;
  int n0 = blockIdx.x * 128;
  int w = tid >> 6;
  int lane = tid & 63;
  int l15 = lane & 15;
  int hi8 = (lane >> 4) << 3;
  sstat[tid] = 0.f;

  // stage z tile (bf16) -> LDS
  for (int i = tid; i < 2048; i += 256) {
    int r = i >> 4, c8 = (i & 15) << 3;
    ushort8v v = {0, 0, 0, 0, 0, 0, 0, 0};
    if (n0 + r < N) v = *(const ushort8v*)&zio[(size_t)(n0 + r) * 128 + c8];
    *(ushort8v*)&zt[r * 136 + c8] = v;
  }
  __syncthreads();

  // ---- GEMM1: t = relu(z @ W1 + b1) ----
  f32x4 acc[2][8];
#pragma unroll
  for (int mf = 0; mf < 2; ++mf)
#pragma unroll
    for (int nf = 0; nf < 8; ++nf) acc[mf][nf] = (f32x4){0.f, 0.f, 0.f, 0.f};
#pragma unroll
  for (int kt = 0; kt < 4; ++kt) {
    int kk = kt * 32 + hi8;
    short8v a0 = *(const short8v*)&zt[(w * 32 + l15) * 136 + kk];
    short8v a1 = *(const short8v*)&zt[(w * 32 + 16 + l15) * 136 + kk];
#pragma unroll
    for (int nf = 0; nf < 8; ++nf) {
      short8v b = *(const short8v*)&WtA[(size_t)(nf * 16 + l15) * 128 + kk];
      acc[0][nf] = __builtin_amdgcn_mfma_f32_16x16x32_bf16(a0, b, acc[0][nf], 0, 0, 0);
      acc[1][nf] = __builtin_amdgcn_mfma_f32_16x16x32_bf16(a1, b, acc[1][nf], 0, 0, 0);
    }
  }
#pragma unroll
  for (int nf = 0; nf < 8; ++nf) {
    float bv = b1[nf * 16 + l15];
    int col = nf * 16 + l15;
#pragma unroll
    for (int mf = 0; mf < 2; ++mf)
#pragma unroll
      for (int q = 0; q < 4; ++q) {
        int row = w * 32 + mf * 16 + (lane >> 4) * 4 + q;
        tt[row * 136 + col] = f2bf(fmaxf(acc[mf][nf][q] + bv, 0.f));
      }
  }
  __syncthreads();

  // ---- GEMM2: u = relu(t @ W2 + b2) ----
#pragma unroll
  for (int mf = 0; mf < 2; ++mf)
#pragma unroll
    for (int nf = 0; nf < 8; ++nf) acc[mf][nf] = (f32x4){0.f, 0.f, 0.f, 0.f};
#pragma unroll
  for (int kt = 0; kt < 4; ++kt) {
    int kk = kt * 32 + hi8;
    short8v a0 = *(const short8v*)&tt[(w * 32 + l15) * 136 + kk];
    short8v a1 = *(const short8v*)&tt[(w * 32 + 16 + l15) * 136 + kk];
#pragma unroll
    for (int nf = 0; nf < 8; ++nf) {
      short8v b = *(const short8v*)&WtB[(size_t)(nf * 16 + l15) * 128 + kk];
      acc[0][nf] = __builtin_amdgcn_mfma_f32_16x16x32_bf16(a0, b, acc[0][nf], 0, 0, 0);
      acc[1][nf] = __builtin_amdgcn_mfma_f32_16x16x32_bf16(a1, b, acc[1][nf], 0, 0, 0);
    }
  }

  // epilogue: relu + bias, BN partial stats, u -> zt (for coalesced store)
#pragma unroll
  for (int nf = 0; nf < 8; ++nf) {
    float bv = b2[nf * 16 + l15];
    int col = nf * 16 + l15;
    float s = 0.f, sq = 0.f;
#pragma unroll
    for (int mf = 0; mf < 2; ++mf)
#pragma unroll
      for (int q = 0; q < 4; ++q) {
        int row = w * 32 + mf * 16 + (lane >> 4) * 4 + q;
        float u = fmaxf(acc[mf][nf][q] + bv, 0.f);
        zt[row * 136 + col] = f2bf(u);
        bool ok = (n0 + row) < N;
        float um = ok ? u : 0.f;
        s += um;
        sq += um * um;
      }
    s += __shfl_xor(s, 16); s += __shfl_xor(s, 32);
    sq += __shfl_xor(sq, 16); sq += __shfl_xor(sq, 32);
    if (lane < 16) {
      atomicAdd(&sstat[col], s);
      atomicAdd(&sstat[128 + col], sq);
    }
  }
  __syncthreads();

  // coalesced u store + global stats
  for (int i = tid; i < 2048; i += 256) {
    int r = i >> 4, c8 = (i & 15) << 3;
    if (n0 + r < N)
      *(ushort8v*)&zio[(size_t)(n0 + r) * 128 + c8] = *(const ushort8v*)&zt[r * 136 + c8];
  }
  atomicAdd(&gstats[tid], sstat[tid]);
}

// ---------------- BN finalize ----------------

__global__ __launch_bounds__(128) void bn_finalize_kernel(float* __restrict__ gstats,
                                                          const float* __restrict__ gamma,
                                                          const float* __restrict__ beta,
                                                          float invN) {
  int d = threadIdx.x;
  float mu = gstats[d] * invN;
  float var = gstats[128 + d] * invN - mu * mu;
  float sc = gamma[d] * rsqrtf(var + BN_EPS);
  gstats[256 + d] = sc;
  gstats[384 + d] = beta[d] - mu * sc;
}

// ---------------- BN apply + segment pool (batch sorted) ----------------
// layers 0,1: write h as bf16 (next agg input); layer 2: write h as f32 to d_out

__global__ __launch_bounds__(256) void bn_pool_kernel(const unsigned short* __restrict__ u,
                                                      const float* __restrict__ gstats,
                                                      const int* __restrict__ batch,
                                                      unsigned short* __restrict__ hbf,
                                                      float* __restrict__ hf32,
                                                      float* __restrict__ pool,
                                                      int poolcol, int N, int usef32) {
  int d = threadIdx.x & 127;
  int half = threadIdx.x >> 7;
  int base = blockIdx.x * 256;
  float sc = gstats[256 + d], sh = gstats[384 + d];
  int curg = -1;
  float accp = 0.f;
  for (int r = half; r < 256; r += 2) {
    int n = base + r;
    if (n >= N) break;
    float uv = bflo((unsigned int)u[(size_t)n * 128 + d]);
    float h = uv * sc + sh;
    if (usef32) hf32[(size_t)n * 128 + d] = h;
    else hbf[(size_t)n * 128 + d] = f2bf(h);
    int g = batch[n];
    if (g != curg) {
      if (curg >= 0) atomicAdd(&pool[(size_t)curg * (NLAYERS * DIM) + poolcol + d], accp);
      curg = g;
      accp = 0.f;
    }
    accp += h;
  }
  if (curg >= 0) atomicAdd(&pool[(size_t)curg * (NLAYERS * DIM) + poolcol + d], accp);
}

// ---------------- launch ----------------

extern "C" void kernel_launch(void* const* d_in, const int* in_sizes, int n_in,
                              void* d_out, int out_size, void* d_ws, size_t ws_size,
                              hipStream_t stream) {
  const float* x = (const float*)d_in[0];
  const int* edge = (const int*)d_in[1];
  const int* batch = (const int*)d_in[2];
  const float* W1 = (const float*)d_in[3];
  const float* b1 = (const float*)d_in[4];
  const float* W2 = (const float*)d_in[5];
  const float* b2 = (const float*)d_in[6];
  const float* gamma = (const float*)d_in[7];
  const float* beta = (const float*)d_in[8];

  int N = in_sizes[0] / DIM;
  int E = in_sizes[1] / 2;
  const int* src = edge;
  const int* dst = edge + E;

  int* deg = (int*)d_ws;
  int* offsets = deg + N;
  int* cursor = offsets + N + 4;
  int* eidx = cursor + N;
  float* gstats = (float*)(eidx + E);
  int* partials = (int*)(gstats + 512);
  unsigned short* Wt = (unsigned short*)(partials + 128);
  unsigned short* zbf = Wt + 6 * 16384;
  unsigned short* hbf = zbf + (size_t)N * 128;

  float* pool = (float*)d_out;
  float* hout = (float*)d_out + (size_t)NGRAPHS * NLAYERS * DIM;

  hipMemsetAsync(deg, 0, (size_t)N * 4, stream);
  hipMemsetAsync(pool, 0, (size_t)NGRAPHS * NLAYERS * DIM * 4, stream);

  int eb = (E + 255) / 256;
  int B1 = (N + 1023) / 1024;
  hist_kernel<<<eb, 256, 0, stream>>>(dst, deg, E);
  red_kernel<<<B1, 256, 0, stream>>>(deg, partials, N);
  scanpart_kernel<<<1, 128, 0, stream>>>(partials, B1);
  bscan_kernel<<<B1, 256, 0, stream>>>(deg, partials, offsets, cursor, N);
  scatter_kernel<<<eb, 256, 0, stream>>>(src, dst, cursor, eidx, E);

  convw_kernel<<<6, 256, 0, stream>>>(W1, W2, Wt);
  convx_kernel<<<(N * DIM / 4 + 255) / 256, 256, 0, stream>>>(x, hbf, N * DIM / 4);

  for (int L = 0; L < NLAYERS; ++L) {
    agg_kernel<<<(N + 3) / 4, 256, 0, stream>>>(hbf, offsets, eidx, zbf, gstats, N);
    mlp_kernel<<<(N + 127) / 128, 256, 0, stream>>>(zbf, Wt + (size_t)L * 16384,
                                                    b1 + L * DIM, Wt + (size_t)(3 + L) * 16384,
                                                    b2 + L * DIM, gstats, N);
    bn_finalize_kernel<<<1, 128, 0, stream>>>(gstats, gamma + L * DIM, beta + L * DIM,
                                              1.0f / (float)N);
    bn_pool_kernel<<<(N + 255) / 256, 256, 0, stream>>>(zbf, gstats, batch, hbf, hout, pool,
                                                        L * DIM, N, (L == NLAYERS - 1) ? 1 : 0);
  }
}

// Round 3
// 633.278 us; speedup vs baseline: 2.2589x; 1.3148x over previous
//
#include <hip/hip_runtime.h>

#define DIM 128
#define NLAYERS 3
#define NGRAPHS 128
#define BN_EPS 1e-5f

typedef __attribute__((ext_vector_type(8))) short short8v;
typedef __attribute__((ext_vector_type(8))) unsigned short ushort8v;
typedef __attribute__((ext_vector_type(4))) float f32x4;

__device__ __forceinline__ unsigned short f2bf(float f) {
  unsigned int x = __float_as_uint(f);
  unsigned int r = (x + 0x7fffu + ((x >> 16) & 1u)) >> 16;  // RTNE
  return (unsigned short)r;
}
__device__ __forceinline__ float bflo(unsigned int u) { return __uint_as_float(u << 16); }
__device__ __forceinline__ float bfhi(unsigned int u) { return __uint_as_float(u & 0xffff0000u); }

// ---------------- CSR build via bucketed counting sort ----------------
// phase 1: partition edges into buckets of 1024 dst nodes, packed pair = (dstLocal<<20)|src

#define P1CH 4096

__global__ __launch_bounds__(256) void p1_kernel(const int* __restrict__ src,
                                                 const int* __restrict__ dst,
                                                 int* __restrict__ bucketCursor,
                                                 unsigned int* __restrict__ pairs,
                                                 int stride, int E, int NB) {
  __shared__ int cnt[128];
  __shared__ int base[128];
  int t = threadIdx.x;
  int e0 = blockIdx.x * P1CH;
  int e1 = min(e0 + P1CH, E);
  if (t < NB) cnt[t] = 0;
  __syncthreads();
  for (int e = e0 + t; e < e1; e += 256) atomicAdd(&cnt[dst[e] >> 10], 1);
  __syncthreads();
  if (t < NB) {
    base[t] = atomicAdd(&bucketCursor[t], cnt[t]);
    cnt[t] = 0;
  }
  __syncthreads();
  for (int e = e0 + t; e < e1; e += 256) {
    int d = dst[e];
    int b = d >> 10;
    int p = atomicAdd(&cnt[b], 1) + base[b];
    pairs[(size_t)b * stride + p] = ((unsigned int)(d & 1023) << 20) | (unsigned int)src[e];
  }
}

// scan bucket sizes -> bucket edge bases; also offsets[N] = E
__global__ __launch_bounds__(128) void bscan2_kernel(const int* __restrict__ bucketCursor,
                                                     int* __restrict__ bucketBase,
                                                     int* __restrict__ offsets, int NB, int N) {
  __shared__ int p[128];
  int t = threadIdx.x;
  p[t] = (t < NB) ? bucketCursor[t] : 0;
  __syncthreads();
  for (int off = 1; off < 128; off <<= 1) {
    int v = (t >= off) ? p[t - off] : 0;
    __syncthreads();
    p[t] += v;
    __syncthreads();
  }
  if (t < NB) bucketBase[t] = (t == 0) ? 0 : p[t - 1];
  if (t == 0) offsets[N] = p[127];
}

// phase 2: per-bucket counting sort fully in LDS (1024 bins), emit CSR offsets + eidx
__global__ __launch_bounds__(1024) void p2_kernel(const unsigned int* __restrict__ pairs,
                                                  const int* __restrict__ bucketCursor,
                                                  const int* __restrict__ bucketBase,
                                                  int stride, int* __restrict__ offsets,
                                                  int* __restrict__ eidx, int N) {
  __shared__ int cur[1024];
  int b = blockIdx.x;
  int t = threadIdx.x;
  int sz = bucketCursor[b];
  int ebase = bucketBase[b];
  const unsigned int* pp = pairs + (size_t)b * stride;
  cur[t] = 0;
  __syncthreads();
  for (int i = t; i < sz; i += 1024) atomicAdd(&cur[pp[i] >> 20], 1);
  __syncthreads();
  int v = cur[t];
  __syncthreads();
  cur[t] = v;
  __syncthreads();
  for (int off = 1; off < 1024; off <<= 1) {
    int u = (t >= off) ? cur[t - off] : 0;
    __syncthreads();
    cur[t] += u;
    __syncthreads();
  }
  int excl = cur[t] - v;
  int node = b * 1024 + t;
  if (node < N) offsets[node] = ebase + excl;
  cur[t] = excl;
  __syncthreads();
  for (int i = t; i < sz; i += 1024) {
    unsigned int pv = pp[i];
    int p = atomicAdd(&cur[pv >> 20], 1);
    eidx[ebase + p] = (int)(pv & 0xFFFFFu);
  }
}

// ---------------- conversions ----------------

__global__ __launch_bounds__(256) void convx_kernel(const float* __restrict__ x,
                                                    unsigned short* __restrict__ out,
                                                    int nquads) {
  int i = blockIdx.x * 256 + threadIdx.x;
  if (i < nquads) {
    float4 v = ((const float4*)x)[i];
    ushort4 o;
    o.x = f2bf(v.x); o.y = f2bf(v.y); o.z = f2bf(v.z); o.w = f2bf(v.w);
    ((ushort4*)out)[i] = o;
  }
}

// transpose+convert 6 weight matrices [128][128]: Wt[m][n][k] = W[k][n]
__global__ __launch_bounds__(256) void convw_kernel(const float* __restrict__ W1,
                                                    const float* __restrict__ W2,
                                                    unsigned short* __restrict__ Wt) {
  int m = blockIdx.x;
  const float* W = (m < 3) ? (W1 + (size_t)m * 16384) : (W2 + (size_t)(m - 3) * 16384);
  unsigned short* out = Wt + (size_t)m * 16384;
  __shared__ unsigned short t[128 * 130];
  for (int i = threadIdx.x; i < 16384; i += 256) {
    int k = i >> 7, n = i & 127;
    t[n * 130 + k] = f2bf(W[i]);
  }
  __syncthreads();
  for (int i = threadIdx.x; i < 16384; i += 256) {
    int n = i >> 7, k = i & 127;
    out[i] = t[n * 130 + k];
  }
}

// ---------------- aggregation with fused BN of previous layer ----------------
// z = scPrev*(u_i + sum_j u_j) + (1+deg)*shPrev   (u is pre-BN activations)

__global__ __launch_bounds__(256) void agg_kernel(const unsigned short* __restrict__ uin,
                                                  const int* __restrict__ offsets,
                                                  const int* __restrict__ eidx,
                                                  unsigned short* __restrict__ zout,
                                                  const float* __restrict__ statsPrev,
                                                  const float* __restrict__ gammaPrev,
                                                  const float* __restrict__ betaPrev,
                                                  float* __restrict__ statsCur,
                                                  float invN, int isFirst, int N) {
  int tid = threadIdx.x;
  if (blockIdx.x == 0) statsCur[tid] = 0.f;  // zero sum[128]+sumsq[128] for this layer
  int wid = (blockIdx.x * 256 + tid) >> 6;
  int lane = tid & 63;
  if (wid >= N) return;
  float scx = 1.f, scy = 1.f, shx = 0.f, shy = 0.f;
  if (!isFirst) {
    int d0 = lane * 2, d1 = d0 + 1;
    float mu0 = statsPrev[d0] * invN, mu1 = statsPrev[d1] * invN;
    float v0 = statsPrev[128 + d0] * invN - mu0 * mu0;
    float v1 = statsPrev[128 + d1] * invN - mu1 * mu1;
    scx = gammaPrev[d0] * rsqrtf(v0 + BN_EPS);
    scy = gammaPrev[d1] * rsqrtf(v1 + BN_EPS);
    shx = betaPrev[d0] - mu0 * scx;
    shy = betaPrev[d1] - mu1 * scy;
  }
  const unsigned int* h32 = (const unsigned int*)uin;
  unsigned int own = h32[(size_t)wid * 64 + lane];
  float ax = bflo(own), ay = bfhi(own);
  int beg = offsets[wid], end = offsets[wid + 1];
  int e = beg;
  for (; e + 3 < end; e += 4) {
    int s0 = eidx[e], s1 = eidx[e + 1], s2 = eidx[e + 2], s3 = eidx[e + 3];
    unsigned int u0 = h32[(size_t)s0 * 64 + lane];
    unsigned int u1 = h32[(size_t)s1 * 64 + lane];
    unsigned int u2 = h32[(size_t)s2 * 64 + lane];
    unsigned int u3 = h32[(size_t)s3 * 64 + lane];
    ax += bflo(u0) + bflo(u1) + bflo(u2) + bflo(u3);
    ay += bfhi(u0) + bfhi(u1) + bfhi(u2) + bfhi(u3);
  }
  for (; e < end; ++e) {
    unsigned int u0 = h32[(size_t)eidx[e] * 64 + lane];
    ax += bflo(u0);
    ay += bfhi(u0);
  }
  float degp1 = (float)(end - beg + 1);
  float zx = scx * ax + degp1 * shx;
  float zy = scy * ay + degp1 * shy;
  unsigned int packed = (unsigned int)f2bf(zx) | ((unsigned int)f2bf(zy) << 16);
  ((unsigned int*)zout)[(size_t)wid * 64 + lane] = packed;
}

// ---------------- fused MLP via MFMA: u = relu(relu(z@W1+b1)@W2+b2) ----------------

__global__ __launch_bounds__(256) void mlp_kernel(unsigned short* __restrict__ zio,
                                                  const unsigned short* __restrict__ WtA,
                                                  const float* __restrict__ b1,
                                                  const unsigned short* __restrict__ WtB,
                                                  const float* __restrict__ b2,
                                                  float* __restrict__ gstats, int N) {
  __shared__ unsigned short zt[128 * 136];
  __shared__ unsigned short tt[128 * 136];
  __shared__ float sstat[256];
  int tid = threadIdx.x;
  int n0 = blockIdx.x * 128;
  int w = tid >> 6;
  int lane = tid & 63;
  int l15 = lane & 15;
  int hi8 = (lane >> 4) << 3;
  sstat[tid] = 0.f;

  for (int i = tid; i < 2048; i += 256) {
    int r = i >> 4, c8 = (i & 15) << 3;
    ushort8v v = {0, 0, 0, 0, 0, 0, 0, 0};
    if (n0 + r < N) v = *(const ushort8v*)&zio[(size_t)(n0 + r) * 128 + c8];
    *(ushort8v*)&zt[r * 136 + c8] = v;
  }
  __syncthreads();

  f32x4 acc[2][8];
#pragma unroll
  for (int mf = 0; mf < 2; ++mf)
#pragma unroll
    for (int nf = 0; nf < 8; ++nf) acc[mf][nf] = (f32x4){0.f, 0.f, 0.f, 0.f};
#pragma unroll
  for (int kt = 0; kt < 4; ++kt) {
    int kk = kt * 32 + hi8;
    short8v a0 = *(const short8v*)&zt[(w * 32 + l15) * 136 + kk];
    short8v a1 = *(const short8v*)&zt[(w * 32 + 16 + l15) * 136 + kk];
#pragma unroll
    for (int nf = 0; nf < 8; ++nf) {
      short8v b = *(const short8v*)&WtA[(size_t)(nf * 16 + l15) * 128 + kk];
      acc[0][nf] = __builtin_amdgcn_mfma_f32_16x16x32_bf16(a0, b, acc[0][nf], 0, 0, 0);
      acc[1][nf] = __builtin_amdgcn_mfma_f32_16x16x32_bf16(a1, b, acc[1][nf], 0, 0, 0);
    }
  }
#pragma unroll
  for (int nf = 0; nf < 8; ++nf) {
    float bv = b1[nf * 16 + l15];
    int col = nf * 16 + l15;
#pragma unroll
    for (int mf = 0; mf < 2; ++mf)
#pragma unroll
      for (int q = 0; q < 4; ++q) {
        int row = w * 32 + mf * 16 + (lane >> 4) * 4 + q;
        tt[row * 136 + col] = f2bf(fmaxf(acc[mf][nf][q] + bv, 0.f));
      }
  }
  __syncthreads();

#pragma unroll
  for (int mf = 0; mf < 2; ++mf)
#pragma unroll
    for (int nf = 0; nf < 8; ++nf) acc[mf][nf] = (f32x4){0.f, 0.f, 0.f, 0.f};
#pragma unroll
  for (int kt = 0; kt < 4; ++kt) {
    int kk = kt * 32 + hi8;
    short8v a0 = *(const short8v*)&tt[(w * 32 + l15) * 136 + kk];
    short8v a1 = *(const short8v*)&tt[(w * 32 + 16 + l15) * 136 + kk];
#pragma unroll
    for (int nf = 0; nf < 8; ++nf) {
      short8v b = *(const short8v*)&WtB[(size_t)(nf * 16 + l15) * 128 + kk];
      acc[0][nf] = __builtin_amdgcn_mfma_f32_16x16x32_bf16(a0, b, acc[0][nf], 0, 0, 0);
      acc[1][nf] = __builtin_amdgcn_mfma_f32_16x16x32_bf16(a1, b, acc[1][nf], 0, 0, 0);
    }
  }

#pragma unroll
  for (int nf = 0; nf < 8; ++nf) {
    float bv = b2[nf * 16 + l15];
    int col = nf * 16 + l15;
    float s = 0.f, sq = 0.f;
#pragma unroll
    for (int mf = 0; mf < 2; ++mf)
#pragma unroll
      for (int q = 0; q < 4; ++q) {
        int row = w * 32 + mf * 16 + (lane >> 4) * 4 + q;
        float u = fmaxf(acc[mf][nf][q] + bv, 0.f);
        zt[row * 136 + col] = f2bf(u);
        bool ok = (n0 + row) < N;
        float um = ok ? u : 0.f;
        s += um;
        sq += um * um;
      }
    s += __shfl_xor(s, 16); s += __shfl_xor(s, 32);
    sq += __shfl_xor(sq, 16); sq += __shfl_xor(sq, 32);
    if (lane < 16) {
      atomicAdd(&sstat[col], s);
      atomicAdd(&sstat[128 + col], sq);
    }
  }
  __syncthreads();

  for (int i = tid; i < 2048; i += 256) {
    int r = i >> 4, c8 = (i & 15) << 3;
    if (n0 + r < N)
      *(ushort8v*)&zio[(size_t)(n0 + r) * 128 + c8] = *(const ushort8v*)&zt[r * 136 + c8];
  }
  atomicAdd(&gstats[tid], sstat[tid]);
}

// ---------------- BN apply (recomputed per block) + segment pool ----------------

__global__ __launch_bounds__(256) void pool_kernel(const unsigned short* __restrict__ u,
                                                   const float* __restrict__ stats,
                                                   const float* __restrict__ gamma,
                                                   const float* __restrict__ beta,
                                                   float invN,
                                                   const int* __restrict__ batch,
                                                   float* __restrict__ hout,
                                                   float* __restrict__ pool,
                                                   int poolcol, int N, int writeH) {
  int d = threadIdx.x & 127;
  int half = threadIdx.x >> 7;
  int base = blockIdx.x * 256;
  float mu = stats[d] * invN;
  float var = stats[128 + d] * invN - mu * mu;
  float sc = gamma[d] * rsqrtf(var + BN_EPS);
  float sh = beta[d] - mu * sc;
  int curg = -1;
  float accp = 0.f;
  for (int r = half; r < 256; r += 2) {
    int n = base + r;
    if (n >= N) break;
    float uv = bflo((unsigned int)u[(size_t)n * 128 + d]);
    float h = uv * sc + sh;
    if (writeH) hout[(size_t)n * 128 + d] = h;
    int g = batch[n];
    if (g != curg) {
      if (curg >= 0) atomicAdd(&pool[(size_t)curg * (NLAYERS * DIM) + poolcol + d], accp);
      curg = g;
      accp = 0.f;
    }
    accp += h;
  }
  if (curg >= 0) atomicAdd(&pool[(size_t)curg * (NLAYERS * DIM) + poolcol + d], accp);
}

// ---------------- launch ----------------

extern "C" void kernel_launch(void* const* d_in, const int* in_sizes, int n_in,
                              void* d_out, int out_size, void* d_ws, size_t ws_size,
                              hipStream_t stream) {
  const float* x = (const float*)d_in[0];
  const int* edge = (const int*)d_in[1];
  const int* batch = (const int*)d_in[2];
  const float* W1 = (const float*)d_in[3];
  const float* b1 = (const float*)d_in[4];
  const float* W2 = (const float*)d_in[5];
  const float* b2 = (const float*)d_in[6];
  const float* gamma = (const float*)d_in[7];
  const float* beta = (const float*)d_in[8];

  int N = in_sizes[0] / DIM;
  int E = in_sizes[1] / 2;
  const int* src = edge;
  const int* dst = edge + E;
  int NB = (N + 1023) >> 10;                     // dst buckets of 1024 nodes (98)
  int stride = E / NB + E / (NB * 4) + 2048;     // per-bucket pair capacity (>>40 sigma slack)

  char* w = (char*)d_ws;
  int* eidx = (int*)w;                w += sizeof(int) * (size_t)E;
  int* offsets = (int*)w;             w += sizeof(int) * (size_t)(N + 8);
  int* bucketCursor = (int*)w;        w += sizeof(int) * 128;
  int* bucketBase = (int*)w;          w += sizeof(int) * 128;
  float* gstats = (float*)w;          w += sizeof(float) * 768;   // 3 layers x (sum128,sumsq128)
  unsigned short* Wt = (unsigned short*)w;  w += sizeof(short) * 6 * 16384;
  uintptr_t a = ((uintptr_t)w + 255) & ~(uintptr_t)255;
  unsigned short* bufA = (unsigned short*)a;
  unsigned short* bufB = bufA + (size_t)N * 128;
  unsigned int* pairs = (unsigned int*)bufA;  // alias: pairs dead before first write to bufA

  float* pool = (float*)d_out;
  float* hout = (float*)d_out + (size_t)NGRAPHS * NLAYERS * DIM;

  hipMemsetAsync(bucketCursor, 0, 128 * sizeof(int), stream);
  hipMemsetAsync(pool, 0, (size_t)NGRAPHS * NLAYERS * DIM * sizeof(float), stream);

  convw_kernel<<<6, 256, 0, stream>>>(W1, W2, Wt);
  convx_kernel<<<(N * DIM / 4 + 255) / 256, 256, 0, stream>>>(x, bufB, N * DIM / 4);

  p1_kernel<<<(E + P1CH - 1) / P1CH, 256, 0, stream>>>(src, dst, bucketCursor, pairs,
                                                       stride, E, NB);
  bscan2_kernel<<<1, 128, 0, stream>>>(bucketCursor, bucketBase, offsets, NB, N);
  p2_kernel<<<NB, 1024, 0, stream>>>(pairs, bucketCursor, bucketBase, stride, offsets,
                                     eidx, N);

  float invN = 1.0f / (float)N;
  for (int L = 0; L < NLAYERS; ++L) {
    unsigned short* uin = (L == 0) ? bufB : ((L == 1) ? bufA : bufB);
    unsigned short* zb = (L == 1) ? bufB : bufA;
    const float* statsPrev = gstats + (size_t)(L == 0 ? 0 : (L - 1)) * 256;
    float* statsCur = gstats + (size_t)L * 256;
    agg_kernel<<<(N + 3) / 4, 256, 0, stream>>>(uin, offsets, eidx, zb,
                                                statsPrev, gamma + (L - 1) * DIM,
                                                beta + (L - 1) * DIM, statsCur,
                                                invN, (L == 0) ? 1 : 0, N);
    mlp_kernel<<<(N + 127) / 128, 256, 0, stream>>>(zb, Wt + (size_t)L * 16384,
                                                    b1 + L * DIM, Wt + (size_t)(3 + L) * 16384,
                                                    b2 + L * DIM, statsCur, N);
    pool_kernel<<<(N + 255) / 256, 256, 0, stream>>>(zb, statsCur, gamma + L * DIM,
                                                     beta + L * DIM, invN, batch, hout, pool,
                                                     L * DIM, N, (L == NLAYERS - 1) ? 1 : 0);
  }
}